// Round 7
// baseline (144.012 us; speedup 1.0000x reference)
//
#include <hip/hip_runtime.h>
#include <hip/hip_bf16.h>
#include <math.h>

// Problem dims
#define T_ 30
#define B_ 32
#define V_ 32
#define F_ 128
#define L_ 256
#define LF_ 64
#define H_ 8
#define DH_ 16
#define HIST_ 10

typedef __attribute__((ext_vector_type(4))) float floatx4;
typedef __attribute__((ext_vector_type(8))) short shortx8;
typedef __attribute__((ext_vector_type(4))) unsigned short ushortx4;

#define MFMA_BF16(a, b, c) __builtin_amdgcn_mfma_f32_16x16x32_bf16(a, b, c, 0, 0, 0)

__device__ inline unsigned short f2bf_rne(float x) {
    unsigned int u = __builtin_bit_cast(unsigned int, x);
    unsigned int r = (u + 0x7fffu + ((u >> 16) & 1u)) >> 16;
    return (unsigned short)r;
}
__device__ inline unsigned short f2bf_trunc(float x) {
    return (unsigned short)(__builtin_bit_cast(unsigned int, x) >> 16);
}
__device__ inline float bf2f(unsigned short u) {
    return __builtin_bit_cast(float, (unsigned int)u << 16);
}
__device__ inline ushortx4 cvt4(floatx4 a) {
    ushortx4 r;
    r.x = f2bf_rne(a.x); r.y = f2bf_rne(a.y);
    r.z = f2bf_rne(a.z); r.w = f2bf_rne(a.w);
    return r;
}

// ---------- fused projections ----------
// blocks 0..127: lane projections -> kproj bf16 [B*L][128], lsvT bf16 [B][128][256]
//                (pre-masked), maskb fp32
// blocks 128..607: vehicle projections -> qhm/rhm bf16 HEAD-MAJOR
//                [(b*H+h)][t][v][16] (q has 0.25*log2e folded), resid bf16
__global__ __launch_bounds__(256, 2) void k_proj(
    const float* __restrict__ lanes, const int* __restrict__ mask,
    const float* __restrict__ veh, const float* __restrict__ ip,
    const float* __restrict__ Wk, const float* __restrict__ bk,
    const float* __restrict__ Wv, const float* __restrict__ bv,
    const float* __restrict__ Wq, const float* __restrict__ bq,
    const float* __restrict__ Wr, const float* __restrict__ br,
    unsigned short* __restrict__ kproj, unsigned short* __restrict__ lsvT,
    float* __restrict__ maskb, unsigned short* __restrict__ qhm,
    unsigned short* __restrict__ rhm, unsigned short* __restrict__ resid) {
    __shared__ unsigned short smem[32768];   // 64 KB union
    __shared__ float mloc[64];
    int tid = threadIdx.x;

    if (blockIdx.x < 128) {
        // ---- lane projections ----
        unsigned short* WkF = smem;          // [(nt*2+ks)*64+lane][8]
        unsigned short* WvF = smem + 8192;
        int m0 = blockIdx.x * 64;
        int b = m0 >> 8;
        if (tid < 64) {
            int row = m0 + tid;
            int any = 0;
#pragma unroll
            for (int hh = 0; hh < HIST_; ++hh) any |= mask[hh * (B_ * L_) + row];
            float fm = any ? 1.0f : 0.0f;
            maskb[row] = fm;
            mloc[tid] = fm;
        }
        for (int g = tid; g < 1024; g += 256) {
            int frag = g >> 6, l = g & 63, cc = l & 15, qq = l >> 4;
            int nt = frag >> 1, ks = frag & 1;
            int n = nt * 16 + cc, k0 = ks * 32 + qq * 8;
            floatx4 a0 = *(const floatx4*)(Wk + n * LF_ + k0);
            floatx4 a1 = *(const floatx4*)(Wk + n * LF_ + k0 + 4);
            *(ushortx4*)(WkF + g * 8) = cvt4(a0);
            *(ushortx4*)(WkF + g * 8 + 4) = cvt4(a1);
            floatx4 b0 = *(const floatx4*)(Wv + n * LF_ + k0);
            floatx4 b1 = *(const floatx4*)(Wv + n * LF_ + k0 + 4);
            *(ushortx4*)(WvF + g * 8) = cvt4(b0);
            *(ushortx4*)(WvF + g * 8 + 4) = cvt4(b1);
        }
        __syncthreads();
        int lane = tid & 63, w = tid >> 6;
        int c = lane & 15, quad = lane >> 4;
        int mw = m0 + w * 16;
        shortx8 aF[2];
#pragma unroll
        for (int ks = 0; ks < 2; ++ks) {
            const float* xp = lanes + (size_t)(mw + c) * LF_ + ks * 32 + quad * 8;
            floatx4 x0 = *(const floatx4*)(xp);
            floatx4 x1 = *(const floatx4*)(xp + 4);
            ushortx4 lo = cvt4(x0), hi = cvt4(x1);
            shortx8 af;
            af[0]=(short)lo.x; af[1]=(short)lo.y; af[2]=(short)lo.z; af[3]=(short)lo.w;
            af[4]=(short)hi.x; af[5]=(short)hi.y; af[6]=(short)hi.z; af[7]=(short)hi.w;
            aF[ks] = af;
        }
        floatx4 mk = *(const floatx4*)(mloc + w * 16 + quad * 4);
        int lbase = (mw & 255) + quad * 4;
#pragma unroll
        for (int nt = 0; nt < 8; ++nt) {
            floatx4 acck = {0.f, 0.f, 0.f, 0.f}, accv = {0.f, 0.f, 0.f, 0.f};
#pragma unroll
            for (int ks = 0; ks < 2; ++ks) {
                shortx8 bkf = *(const shortx8*)(WkF + ((nt * 2 + ks) * 64 + lane) * 8);
                shortx8 bvf = *(const shortx8*)(WvF + ((nt * 2 + ks) * 64 + lane) * 8);
                acck = MFMA_BF16(aF[ks], bkf, acck);
                accv = MFMA_BF16(aF[ks], bvf, accv);
            }
            int n = nt * 16 + c;
            float bkn = bk[n], bvn = bv[n];
            ushortx4 vout;
#pragma unroll
            for (int reg = 0; reg < 4; ++reg) {
                size_t row = mw + quad * 4 + reg;
                kproj[row * F_ + n] = f2bf_rne(acck[reg] + bkn);
                float xv = accv[reg] + bvn;
                float ls = fminf(xv, 0.f) - log1pf(__expf(-fabsf(xv)));
                vout[reg] = (mk[reg] > 0.5f) ? f2bf_rne(ls) : (unsigned short)0;
            }
            *(ushortx4*)(lsvT + ((size_t)b * F_ + n) * L_ + lbase) = vout;
        }
    } else {
        // ---- vehicle projections ----
        unsigned short* WqF = smem;          // [(nt*4+ks)*64+lane][8]
        unsigned short* WrF = smem + 16384;
        for (int g = tid; g < 2048; g += 256) {
            int frag = g >> 6, l = g & 63, cc = l & 15, qq = l >> 4;
            int nt = frag >> 2, ks = frag & 3;
            int n = nt * 16 + cc, k0 = ks * 32 + qq * 8;
            floatx4 a0 = *(const floatx4*)(Wq + n * F_ + k0);
            floatx4 a1 = *(const floatx4*)(Wq + n * F_ + k0 + 4);
            *(ushortx4*)(WqF + g * 8) = cvt4(a0);
            *(ushortx4*)(WqF + g * 8 + 4) = cvt4(a1);
            floatx4 b0 = *(const floatx4*)(Wr + n * F_ + k0);
            floatx4 b1 = *(const floatx4*)(Wr + n * F_ + k0 + 4);
            *(ushortx4*)(WrF + g * 8) = cvt4(b0);
            *(ushortx4*)(WrF + g * 8 + 4) = cvt4(b1);
        }
        __syncthreads();
        int lane = tid & 63, w = tid >> 6;
        int c = lane & 15, quad = lane >> 4;
        int m0 = (blockIdx.x - 128) * 64 + w * 16;
        shortx8 aF[4];
#pragma unroll
        for (int ks = 0; ks < 4; ++ks) {
            size_t off = (size_t)(m0 + c) * F_ + ks * 32 + quad * 8;
            floatx4 v0 = *(const floatx4*)(veh + off);
            floatx4 v1 = *(const floatx4*)(veh + off + 4);
            floatx4 i0 = *(const floatx4*)(ip + off);
            floatx4 i1 = *(const floatx4*)(ip + off + 4);
            ushortx4 lo = cvt4(v0 + i0), hi = cvt4(v1 + i1);
            shortx8 af;
            af[0]=(short)lo.x; af[1]=(short)lo.y; af[2]=(short)lo.z; af[3]=(short)lo.w;
            af[4]=(short)hi.x; af[5]=(short)hi.y; af[6]=(short)hi.z; af[7]=(short)hi.w;
            aF[ks] = af;
            *(ushortx4*)(resid + off) = cvt4(v0 - i0);
            *(ushortx4*)(resid + off + 4) = cvt4(v1 - i1);
        }
        const float QSCALE = 0.25f * 1.4426950408889634f;  // 1/sqrt(DH) * log2(e)
#pragma unroll
        for (int nt = 0; nt < 8; ++nt) {
            floatx4 accq = {0.f, 0.f, 0.f, 0.f}, accr = {0.f, 0.f, 0.f, 0.f};
#pragma unroll
            for (int ks = 0; ks < 4; ++ks) {
                shortx8 bqf = *(const shortx8*)(WqF + ((nt * 4 + ks) * 64 + lane) * 8);
                shortx8 brf = *(const shortx8*)(WrF + ((nt * 4 + ks) * 64 + lane) * 8);
                accq = MFMA_BF16(aF[ks], bqf, accq);
                accr = MFMA_BF16(aF[ks], brf, accr);
            }
            int n = nt * 16 + c;   // h = nt, dh = c
            float bqn = bq[n], brn = br[n];
#pragma unroll
            for (int reg = 0; reg < 4; ++reg) {
                int row = m0 + quad * 4 + reg;
                int t = row >> 10, rem = row & 1023;
                int b = rem >> 5, v = rem & 31;
                // head-major: [(b*8+nt)*30+t][v][dh=c]
                size_t hidx = ((size_t)((b * 8 + nt) * 30 + t) << 9) + (v << 4) + c;
                qhm[hidx] = f2bf_rne((accq[reg] + bqn) * QSCALE);
                rhm[hidx] = f2bf_rne(accr[reg] + brn);
            }
        }
    }
}

// ---------- MFMA attention ----------
// tc=2: 512 blocks (2/CU), K/V staged once, 30 query-tiles per block.
// exp2-domain scores; V pre-masked; denominator via mask-row MFMA; pE
// wave-private frag-order. Software-pipelined: next tile's q/r global loads
// issue before current tile's compute (hides ~300cyc latency at 2 waves/SIMD).
__global__ __launch_bounds__(256, 2) void k_attn(
    const unsigned short* __restrict__ kproj, const unsigned short* __restrict__ lsvT,
    const float* __restrict__ maskb, const unsigned short* __restrict__ qhm,
    const unsigned short* __restrict__ rhm, unsigned short* __restrict__ ratt) {
    __shared__ unsigned short kS[256 * 24];     // [l][16d], stride 24
    __shared__ unsigned short vT[16 * 264];     // [d][l], stride 264
    __shared__ unsigned short pE[4 * 4096];     // per-wave frag-order P

    int tid = threadIdx.x;
    int bh = blockIdx.x & 255;
    int tc = blockIdx.x >> 8;        // 0..1
    int h = bh & 7;
    int b = bh >> 3;

    const unsigned short* kbase = kproj + ((size_t)b * L_) * F_ + h * DH_;
#pragma unroll
    for (int it = 0; it < 2; ++it) {
        int id = it * 256 + tid;
        int l = id >> 1, half = id & 1;
        shortx8 kv = *(const shortx8*)(kbase + (size_t)l * F_ + half * 8);
        *(shortx8*)(kS + l * 24 + half * 8) = kv;
    }
    {
        int d = tid >> 4, c16 = tid & 15;
        const unsigned short* vrow = lsvT + ((size_t)b * F_ + h * DH_ + d) * L_ + c16 * 16;
        shortx8 v0 = *(const shortx8*)(vrow);
        shortx8 v1 = *(const shortx8*)(vrow + 8);
        *(shortx8*)(vT + d * 264 + c16 * 16) = v0;
        *(shortx8*)(vT + d * 264 + c16 * 16 + 8) = v1;
    }
    __syncthreads();

    int lane = tid & 63, w = tid >> 6;
    int c = lane & 15, quad = lane >> 4;

    const unsigned short* qhead = qhm + ((size_t)(b * 8 + h) * 30) * 512;
    const unsigned short* rhead = rhm + ((size_t)(b * 8 + h) * 30) * 512;

    // prologue prefetch for first tile (overlaps fragment builds below)
    shortx8 qF_cur = {0, 0, 0, 0, 0, 0, 0, 0};
    ushortx4 rv_cur;
    {
        int mt = tc * 30 + w;
        int t = mt >> 1, v0 = (mt & 1) * 16;
        size_t qtile = (size_t)t * 512 + v0 * 16;
        if (quad < 2) qF_cur = *(const shortx8*)(qhead + qtile + c * 16 + quad * 8);
        rv_cur = *(const ushortx4*)(rhead + qtile + c * 16 + quad * 4);
    }

    shortx8 kF[16];
#pragma unroll
    for (int lt = 0; lt < 16; ++lt) {
        shortx8 z = {0, 0, 0, 0, 0, 0, 0, 0};
        kF[lt] = (quad < 2) ? *(const shortx8*)(kS + (lt * 16 + c) * 24 + quad * 8) : z;
    }
    shortx8 vF[8];
#pragma unroll
    for (int kk = 0; kk < 8; ++kk)
        vF[kk] = *(const shortx8*)(vT + c * 264 + kk * 32 + quad * 8);
    shortx8 mF[8];
#pragma unroll
    for (int kk = 0; kk < 8; ++kk) {
        const float* mp = maskb + b * L_ + kk * 32 + quad * 8;
        floatx4 ma = *(const floatx4*)(mp);
        floatx4 mb2 = *(const floatx4*)(mp + 4);
        shortx8 mf;
        mf[0]=(short)f2bf_trunc(ma.x); mf[1]=(short)f2bf_trunc(ma.y);
        mf[2]=(short)f2bf_trunc(ma.z); mf[3]=(short)f2bf_trunc(ma.w);
        mf[4]=(short)f2bf_trunc(mb2.x); mf[5]=(short)f2bf_trunc(mb2.y);
        mf[6]=(short)f2bf_trunc(mb2.z); mf[7]=(short)f2bf_trunc(mb2.w);
        mF[kk] = mf;
    }

    unsigned short* pEw = pE + w * 4096;
    // frag-order write slot: addr = (kk*64 + quadp*16 + c)*8 + (quad&1)*4
    int wr_c = c * 8 + (quad & 1) * 4;
    int wr_q = (quad >> 1) * 128;
    floatx4 z4 = {0.f, 0.f, 0.f, 0.f};

    for (int mtl = w; mtl < 30; mtl += 4) {
        int mt = tc * 30 + mtl;              // 0..59
        int t = mt >> 1, v0 = (mt & 1) * 16;

        // prefetch next tile's q/r (independent of current compute)
        shortx8 qF_nxt = {0, 0, 0, 0, 0, 0, 0, 0};
        ushortx4 rv_nxt = {0, 0, 0, 0};
        if (mtl + 4 < 30) {
            int mtn = mt + 4;
            int tn = mtn >> 1, v0n = (mtn & 1) * 16;
            size_t qtn = (size_t)tn * 512 + v0n * 16;
            if (quad < 2) qF_nxt = *(const shortx8*)(qhead + qtn + c * 16 + quad * 8);
            rv_nxt = *(const ushortx4*)(rhead + qtn + c * 16 + quad * 4);
        }

#pragma unroll
        for (int lt = 0; lt < 16; ++lt) {
            floatx4 s = MFMA_BF16(kF[lt], qF_cur, z4);  // S^T[l][q], exp2 domain
            ushortx4 ep;
#pragma unroll
            for (int reg = 0; reg < 4; ++reg)
                ep[reg] = f2bf_trunc(__builtin_amdgcn_exp2f(s[reg]));
            *(ushortx4*)(pEw + (lt >> 1) * 512 + (lt & 1) * 256 + wr_q + wr_c) = ep;
        }

        floatx4 cU = z4, cN = z4;
#pragma unroll
        for (int kk = 0; kk < 8; ++kk) {
            shortx8 bP = *(const shortx8*)(pEw + (kk * 64 + lane) * 8);
            cU = MFMA_BF16(vF[kk], bP, cU);
            cN = MFMA_BF16(mF[kk], bP, cN);
        }
        float inv2 = __builtin_amdgcn_rcpf(cN[0]) * 1.4426950408889634f;
        ushortx4 ob;
#pragma unroll
        for (int reg = 0; reg < 4; ++reg) {
            float att = __builtin_amdgcn_exp2f(cU[reg] * inv2);  // e^(U/sum)
            ob[reg] = f2bf_rne(bf2f(rv_cur[reg]) * att);
        }
        *(ushortx4*)(ratt + (((size_t)t * B_ + b) * H_ + h) * (V_ * DH_)
                    + (v0 + c) * DH_ + quad * 4) = ob;

        qF_cur = qF_nxt;
        rv_cur = rv_nxt;
    }
}

// ---------- combine (MFMA): out = ratt@Wc^T + bc + resid ----------
// (256,4): 4 blocks/CU (128KB LDS total) for latency hiding of global loads.
__global__ __launch_bounds__(256, 4) void k_out(
    const unsigned short* __restrict__ ratt, const float* __restrict__ Wc,
    const float* __restrict__ bc, const unsigned short* __restrict__ resid,
    float* __restrict__ out) {
    __shared__ unsigned short WcF[16384];
    int tid = threadIdx.x;
    for (int g = tid; g < 2048; g += 256) {
        int frag = g >> 6, l = g & 63, cc = l & 15, qq = l >> 4;
        int nt = frag >> 2, ks = frag & 3;
        int n = nt * 16 + cc, k0 = ks * 32 + qq * 8;
        floatx4 a0 = *(const floatx4*)(Wc + n * F_ + k0);
        floatx4 a1 = *(const floatx4*)(Wc + n * F_ + k0 + 4);
        *(ushortx4*)(WcF + g * 8) = cvt4(a0);
        *(ushortx4*)(WcF + g * 8 + 4) = cvt4(a1);
    }
    __syncthreads();
    int lane = tid & 63, w = tid >> 6;
    int c = lane & 15, quad = lane >> 4;
    int m0 = blockIdx.x * 64 + w * 16;
    shortx8 aF[4];
#pragma unroll
    for (int ks = 0; ks < 4; ++ks)
        aF[ks] = *(const shortx8*)(ratt + (size_t)(m0 + c) * F_ + ks * 32 + quad * 8);
#pragma unroll
    for (int np = 0; np < 4; ++np) {
        int nt0 = np * 2, nt1 = np * 2 + 1;
        floatx4 acc0 = {0.f, 0.f, 0.f, 0.f}, acc1 = {0.f, 0.f, 0.f, 0.f};
#pragma unroll
        for (int ks = 0; ks < 4; ++ks) {
            shortx8 b0 = *(const shortx8*)(WcF + ((nt0 * 4 + ks) * 64 + lane) * 8);
            shortx8 b1 = *(const shortx8*)(WcF + ((nt1 * 4 + ks) * 64 + lane) * 8);
            acc0 = MFMA_BF16(aF[ks], b0, acc0);
            acc1 = MFMA_BF16(aF[ks], b1, acc1);
        }
        int n0 = nt0 * 16 + c, n1 = nt1 * 16 + c;
        float bc0 = bc[n0], bc1 = bc[n1];
#pragma unroll
        for (int reg = 0; reg < 4; ++reg) {
            size_t row = m0 + quad * 4 + reg;
            size_t o0 = row * F_ + n0, o1 = row * F_ + n1;
            out[o0] = acc0[reg] + bc0 + bf2f(resid[o0]);
            out[o1] = acc1[reg] + bc1 + bf2f(resid[o1]);
        }
    }
}

extern "C" void kernel_launch(void* const* d_in, const int* in_sizes, int n_in,
                              void* d_out, int out_size, void* d_ws, size_t ws_size,
                              hipStream_t stream) {
    const float* vehicles    = (const float*)d_in[0];
    const float* initial_pos = (const float*)d_in[1];
    const float* lanes       = (const float*)d_in[2];
    const int*   mask        = (const int*)d_in[3];
    const float* Wk = (const float*)d_in[4];
    const float* bk = (const float*)d_in[5];
    const float* Wv = (const float*)d_in[6];
    const float* bv = (const float*)d_in[7];
    const float* Wq = (const float*)d_in[8];
    const float* bq = (const float*)d_in[9];
    const float* Wr = (const float*)d_in[10];
    const float* br = (const float*)d_in[11];
    const float* Wc = (const float*)d_in[12];
    const float* bc = (const float*)d_in[13];
    float* out = (float*)d_out;

    char* p = (char*)d_ws;
    float* maskb = (float*)p;                   p += ((B_ * L_ * 4 + 255) / 256) * 256;
    unsigned short* kproj = (unsigned short*)p; p += ((size_t)B_ * L_ * F_ * 2 + 255) / 256 * 256;
    unsigned short* lsvT  = (unsigned short*)p; p += ((size_t)B_ * F_ * L_ * 2 + 255) / 256 * 256;
    unsigned short* qhm   = (unsigned short*)p; p += ((size_t)T_ * B_ * V_ * F_ * 2 + 255) / 256 * 256;
    unsigned short* rhm   = (unsigned short*)p; p += ((size_t)T_ * B_ * V_ * F_ * 2 + 255) / 256 * 256;
    unsigned short* rattb = (unsigned short*)p; p += ((size_t)T_ * B_ * V_ * F_ * 2 + 255) / 256 * 256;
    unsigned short* resid = (unsigned short*)p; p += ((size_t)T_ * B_ * V_ * F_ * 2 + 255) / 256 * 256;

    k_proj<<<128 + (T_ * B_ * V_) / 64, 256, 0, stream>>>(
        lanes, mask, vehicles, initial_pos, Wk, bk, Wv, bv, Wq, bq, Wr, br,
        kproj, lsvT, maskb, qhm, rhm, resid);
    k_attn<<<2 * B_ * H_, 256, 0, stream>>>(kproj, lsvT, maskb, qhm, rhm, rattb);
    k_out<<<(T_ * B_ * V_) / 64, 256, 0, stream>>>(rattb, Wc, bc, resid, out);
}